// Round 2
// baseline (158.519 us; speedup 1.0000x reference)
//
#include <hip/hip_runtime.h>
#include <stdint.h>

// Problem constants (B=8, K=4, N=131072)
#define NPER      131072      // N = 2^17
#define NTOT      4194304LL   // B*K*N
#define CHUNK     2048
#define NBLK      2048        // NTOT / CHUNK
#define ROUNDS    8           // CHUNK / 256
#define NEG_PAD   (-1000.0f)
#define NEG_IDLE  (-100000000.0f)

// ---------------------------------------------------------------------------
// Pass 1: per-block mask counts. Masks are int32 (harness materializes bool
// as int). Each block counts a 2048-element chunk of both masks; result
// packed as cnt_s | (cnt_a << 32) into sums[blk].
// ---------------------------------------------------------------------------
__global__ __launch_bounds__(256) void count_kernel(
    const int* __restrict__ ms, const int* __restrict__ ma,
    unsigned long long* __restrict__ sums)
{
    long long base = (long long)blockIdx.x * CHUNK;
    const int4* ms4 = (const int4*)(ms + base);
    const int4* ma4 = (const int4*)(ma + base);
    int t = threadIdx.x;
    int4 s0 = ms4[2 * t], s1 = ms4[2 * t + 1];
    int4 a0 = ma4[2 * t], a1 = ma4[2 * t + 1];
    unsigned cs = (s0.x != 0) + (s0.y != 0) + (s0.z != 0) + (s0.w != 0)
                + (s1.x != 0) + (s1.y != 0) + (s1.z != 0) + (s1.w != 0);
    unsigned ca = (a0.x != 0) + (a0.y != 0) + (a0.z != 0) + (a0.w != 0)
                + (a1.x != 0) + (a1.y != 0) + (a1.z != 0) + (a1.w != 0);
    unsigned packed = cs | (ca << 16);   // per-thread <=8 each, block <=2048: fits 16b
    #pragma unroll
    for (int off = 32; off > 0; off >>= 1)
        packed += __shfl_down(packed, off, 64);
    __shared__ unsigned lds[4];
    int lane = t & 63, wave = t >> 6;
    if (lane == 0) lds[wave] = packed;
    __syncthreads();
    if (t == 0) {
        unsigned tot = lds[0] + lds[1] + lds[2] + lds[3];
        sums[blockIdx.x] = (unsigned long long)(tot & 0xffffu)
                         | ((unsigned long long)(tot >> 16) << 32);
    }
}

// ---------------------------------------------------------------------------
// Pass 2: exclusive scan of the 2048 packed block sums, in place.
// Per-mask totals (<=4.19M) fit in 32-bit halves -> one u64 scan does both.
// ---------------------------------------------------------------------------
__global__ __launch_bounds__(1024) void scan_kernel(unsigned long long* __restrict__ sums)
{
    __shared__ unsigned long long lds[1024];
    int t = threadIdx.x;
    unsigned long long v0 = sums[2 * t], v1 = sums[2 * t + 1];
    unsigned long long pair = v0 + v1;
    unsigned long long x = pair;
    lds[t] = x;
    __syncthreads();
    for (int off = 1; off < 1024; off <<= 1) {
        unsigned long long y = (t >= off) ? lds[t - off] : 0ULL;
        __syncthreads();
        x += y;
        lds[t] = x;
        __syncthreads();
    }
    unsigned long long excl = x - pair;          // exclusive prefix of the pair
    sums[2 * t]     = excl;
    sums[2 * t + 1] = excl + v0;
}

// ---------------------------------------------------------------------------
// Pass 3: expand + write. 8 rounds of 256 coalesced elements per block.
// Per round: block-exclusive scan of packed (s | a<<16) gives each lane its
// local rank; + scanned block offset = global compacted index. Gather index
// clipped to [0, ts-1] / [0, ta-1] to replicate _expand's jnp.clip (the
// harness's mask counts can exceed the traced value-array lengths).
// ---------------------------------------------------------------------------
__global__ __launch_bounds__(256) void write_kernel(
    const float* __restrict__ rgb, const float* __restrict__ lsurf,
    const float* __restrict__ lair, const float* __restrict__ idle,
    const int* __restrict__ ms, const int* __restrict__ ma,
    const unsigned long long* __restrict__ offs,
    unsigned ts_max, unsigned ta_max,      // ts-1, ta-1
    float* __restrict__ out_rgb, float* __restrict__ out_ls, float* __restrict__ out_la)
{
    __shared__ unsigned wsum[4];
    long long base = (long long)blockIdx.x * CHUNK;
    int bk = (int)(base >> 17);                  // N = 2^17; chunk within one (b,k) row
    float idle_v    = idle[bk];
    float alive     = 1.0f - idle_v;
    float idle_term = idle_v * NEG_IDLE;
    unsigned long long off64 = offs[blockIdx.x];
    unsigned baseS = (unsigned)(off64 & 0xffffffffULL);
    unsigned baseA = (unsigned)(off64 >> 32);
    int lane = threadIdx.x & 63, wave = threadIdx.x >> 6;

    for (int r = 0; r < ROUNDS; ++r) {
        long long i = base + (long long)r * 256 + threadIdx.x;
        unsigned s = (ms[i] != 0) ? 1u : 0u;
        unsigned a = (ma[i] != 0) ? 1u : 0u;
        unsigned packed = s | (a << 16);
        // inclusive wave scan (fields max 64/wave, 256/block -> no cross-field carry)
        unsigned x = packed;
        #pragma unroll
        for (int off = 1; off < 64; off <<= 1) {
            unsigned y = __shfl_up(x, off, 64);
            if (lane >= off) x += y;
        }
        if (lane == 63) wsum[wave] = x;
        __syncthreads();
        unsigned w0 = wsum[0], w1 = wsum[1], w2 = wsum[2], w3 = wsum[3];
        __syncthreads();                         // wsum reused next round
        unsigned pre  = (wave > 0 ? w0 : 0u) + (wave > 1 ? w1 : 0u) + (wave > 2 ? w2 : 0u);
        unsigned excl = pre + x - packed;
        unsigned total = w0 + w1 + w2 + w3;
        unsigned ps = min(baseS + (excl & 0xffffu), ts_max);
        unsigned pa = min(baseA + (excl >> 16),     ta_max);

        float r0 = 0.f, r1 = 0.f, r2 = 0.f, lso = NEG_PAD, lao = NEG_PAD;
        if (s) {
            r0  = rgb[3 * (long long)ps]     * alive;
            r1  = rgb[3 * (long long)ps + 1] * alive;
            r2  = rgb[3 * (long long)ps + 2] * alive;
            lso = lsurf[ps] * alive + idle_term;
        }
        if (a) lao = lair[pa] * alive + idle_term;

        long long i3 = i * 3;
        out_rgb[i3]     = r0;
        out_rgb[i3 + 1] = r1;
        out_rgb[i3 + 2] = r2;
        out_ls[i] = lso;
        out_la[i] = lao;

        baseS += total & 0xffffu;
        baseA += total >> 16;
    }
}

extern "C" void kernel_launch(void* const* d_in, const int* in_sizes, int n_in,
                              void* d_out, int out_size, void* d_ws, size_t ws_size,
                              hipStream_t stream)
{
    const float* rgb   = (const float*)d_in[0];
    const float* lsurf = (const float*)d_in[1];
    const float* lair  = (const float*)d_in[2];
    const float* idle  = (const float*)d_in[3];
    const int*   ms    = (const int*)d_in[4];   // bool -> int32 per harness contract
    const int*   ma    = (const int*)d_in[5];

    unsigned ts_max = (unsigned)(in_sizes[1] - 1);   // logits_surface: (ts,1)
    unsigned ta_max = (unsigned)(in_sizes[2] - 1);   // logits_air:     (ta,1)

    float* out     = (float*)d_out;
    float* out_rgb = out;                  // (B,K,N,3)
    float* out_ls  = out + NTOT * 3;       // (B,K,N,1)
    float* out_la  = out_ls + NTOT;        // (B,K,N,1)

    unsigned long long* sums = (unsigned long long*)d_ws;   // 2048 * 8 B = 16 KB

    count_kernel<<<NBLK, 256, 0, stream>>>(ms, ma, sums);
    scan_kernel<<<1, 1024, 0, stream>>>(sums);
    write_kernel<<<NBLK, 256, 0, stream>>>(rgb, lsurf, lair, idle, ms, ma, sums,
                                           ts_max, ta_max, out_rgb, out_ls, out_la);
}